// Round 5
// baseline (239.754 us; speedup 1.0000x reference)
//
#include <hip/hip_runtime.h>

#define NN 20
#define NP 125          // 5^3 window
#define NV (NN*NN*NN)   // 8000

// ---------------------------------------------------------------------------
// prep: blocks 0..124  -> k_rel[p][c]  = bk + relpos_flat[p] @ Wk[0:96]
//                         vrelW[p][c]  = (bv + relpos_flat[p] @ Wv[0:96]) @ Wo
//       blocks 125..188 -> Wvo[d][c]   = Wv[96+d][:] @ Wo     (64x64)
// ---------------------------------------------------------------------------
__global__ __launch_bounds__(64) void prep(
        const float* __restrict__ rpw,
        const float* __restrict__ Wk, const float* __restrict__ bk,
        const float* __restrict__ Wv, const float* __restrict__ bv,
        const float* __restrict__ Wo,
        float* __restrict__ k_rel, float* __restrict__ vrelW,
        float* __restrict__ Wvo) {
    const int c = threadIdx.x;
    if (blockIdx.x < NP) {
        const int p = blockIdx.x;
        const int d3 = p / 25, d4 = (p / 5) % 5, d5 = p % 5;
        __shared__ float vtmp[64];
        float ak = bk[c], av = bv[c];
#pragma unroll
        for (int t = 0; t < 96; ++t) {
            const int blk = t >> 5, off = t & 31;
            const int row = (blk == 0) ? d3 : (blk == 1) ? d4 : d5;
            const float r = rpw[row * 32 + off];
            ak = fmaf(r, Wk[t * 64 + c], ak);
            av = fmaf(r, Wv[t * 64 + c], av);
        }
        k_rel[p * 64 + c] = ak;
        vtmp[c] = av;
        __syncthreads();
        float o = 0.f;
#pragma unroll 8
        for (int e = 0; e < 64; ++e)
            o = fmaf(vtmp[e], Wo[e * 64 + c], o);
        vrelW[p * 64 + c] = o;
    } else {
        const int d = blockIdx.x - NP;
        float acc = 0.f;
#pragma unroll 8
        for (int e = 0; e < 64; ++e)
            acc = fmaf(Wv[(96 + d) * 64 + e], Wo[e * 64 + c], acc);
        Wvo[d * 64 + c] = acc;
    }
}

// ---------------------------------------------------------------------------
// qkv2: Q = SE@Wq + bq ; Km = SE@Wk[96:] ; VW = SE@Wvo
// 250 blocks x 256 threads, 32 voxels/block (8 per wave).
// ---------------------------------------------------------------------------
__global__ __launch_bounds__(256) void qkv2(
        const float* __restrict__ SE,
        const float* __restrict__ Wq, const float* __restrict__ bq,
        const float* __restrict__ Wk, const float* __restrict__ Wvo,
        float* __restrict__ Q, float* __restrict__ Km, float* __restrict__ VW) {
    __shared__ float se_s[32][65];
    const int t = threadIdx.x;
    const int vbase = blockIdx.x * 32;
    {   // stage 32x64 floats = 512 float4, 2 per thread
        const float4* __restrict__ src = (const float4*)(SE + vbase * 64);
        const float4 a = src[t];
        const float4 b = src[t + 256];
        const int r0 = t >> 4,        c0 = (t & 15) * 4;
        const int r1 = (t + 256) >> 4;
        se_s[r0][c0 + 0] = a.x; se_s[r0][c0 + 1] = a.y;
        se_s[r0][c0 + 2] = a.z; se_s[r0][c0 + 3] = a.w;
        se_s[r1][c0 + 0] = b.x; se_s[r1][c0 + 1] = b.y;
        se_s[r1][c0 + 2] = b.z; se_s[r1][c0 + 3] = b.w;
    }
    __syncthreads();
    const int lane = t & 63, w = t >> 6;
    float aq[8], ak[8], av[8];
#pragma unroll
    for (int j = 0; j < 8; ++j) { aq[j] = bq[lane]; ak[j] = 0.f; av[j] = 0.f; }
#pragma unroll 8
    for (int d = 0; d < 64; ++d) {
        const float wq = Wq[d * 64 + lane];
        const float wk = Wk[(96 + d) * 64 + lane];
        const float wv = Wvo[d * 64 + lane];
#pragma unroll
        for (int j = 0; j < 8; ++j) {
            const float s = se_s[w * 8 + j][d];   // uniform addr -> broadcast
            aq[j] = fmaf(s, wq, aq[j]);
            ak[j] = fmaf(s, wk, ak[j]);
            av[j] = fmaf(s, wv, av[j]);
        }
    }
#pragma unroll
    for (int j = 0; j < 8; ++j) {
        const int v = vbase + w * 8 + j;
        Q[v * 64 + lane]  = aq[j];
        Km[v * 64 + lane] = ak[j];
        VW[v * 64 + lane] = av[j];
    }
}

// ---------------------------------------------------------------------------
// attn3: block = 512 threads (8 waves) = 2x2x2 voxel tile. Grid 10x10x10.
// All gathers via LDS. One padded union buffer u[216 rows][65] reused in 3
// staged phases (k_rel -> Km-union -> VW-union); row stride 65 floats makes
// bank = (row+lane)%32 -> conflict-free. OOB union rows are zero-filled,
// matching the reference's zero padding, so compute needs no gating.
// REFERENCE QUIRKS: gather coord = (x+e4-2, y+e3-2, z+e5-2) [x/y digit swap];
// mask coord = (x+e3-2, y+e4-2, z+e5-2) must lie in [1,19]^3.
// Masked logit -1e9 -> score exactly 0 -> branch-free V accumulation.
// ---------------------------------------------------------------------------
__global__ __launch_bounds__(512, 4) void attn3(
        const float* __restrict__ Q, const float* __restrict__ Km,
        const float* __restrict__ VW,
        const float* __restrict__ k_rel, const float* __restrict__ vrelW,
        const float* __restrict__ bo,
        float* __restrict__ out) {
    __shared__ float u[216 * 65];
    __shared__ float sc_s[8][128];

    const int tid  = threadIdx.x;
    const int lane = tid & 63;
    const int w    = tid >> 6;
    const int bx = blockIdx.x;
    const int TX = bx / 100, TY = (bx / 10) % 10, TZ = bx % 10;
    const int wx = w >> 2, wy = (w >> 1) & 1, wz = w & 1;
    const int x = TX * 2 + wx, y = TY * 2 + wy, z = TZ * 2 + wz;
    const int v = (x * NN + y) * NN + z;

    // ---- phase A: stage k_rel (125 rows) ----
    for (int i = tid; i < 125 * 16; i += 512) {
        const int row = i >> 4, ch = i & 15;
        const float4 val = ((const float4*)k_rel)[row * 16 + ch];
        const int b = row * 65 + ch * 4;
        u[b] = val.x; u[b + 1] = val.y; u[b + 2] = val.z; u[b + 3] = val.w;
    }
    __syncthreads();

    const float q = Q[v * 64 + lane];
    const int p0 = lane;
    const int p1 = lane + 64;
    const int p1c = (p1 < NP) ? p1 : (NP - 1);

    float rel0 = 0.f, rel1 = 0.f;
#pragma unroll
    for (int i = 0; i < 16; ++i) {
        const float qa = __shfl(q, 4 * i + 0);
        const float qb = __shfl(q, 4 * i + 1);
        const float qc = __shfl(q, 4 * i + 2);
        const float qd = __shfl(q, 4 * i + 3);
        const int b0 = p0 * 65 + 4 * i;
        const int b1 = p1c * 65 + 4 * i;
        rel0 = fmaf(u[b0], qa, rel0); rel0 = fmaf(u[b0 + 1], qb, rel0);
        rel0 = fmaf(u[b0 + 2], qc, rel0); rel0 = fmaf(u[b0 + 3], qd, rel0);
        rel1 = fmaf(u[b1], qa, rel1); rel1 = fmaf(u[b1 + 1], qb, rel1);
        rel1 = fmaf(u[b1 + 2], qc, rel1); rel1 = fmaf(u[b1 + 3], qd, rel1);
    }
    __syncthreads();   // all reads of u(k_rel) done

    // ---- phase B: stage Km union (216 rows, zero-fill OOB) ----
    for (int i = tid; i < 216 * 16; i += 512) {
        const int row = i >> 4, ch = i & 15;
        const int ux = row / 36, uy = (row / 6) % 6, uz = row % 6;
        const int gX = TX * 2 - 2 + ux;
        const int gY = TY * 2 - 2 + uy;
        const int gZ = TZ * 2 - 2 + uz;
        float4 val = make_float4(0.f, 0.f, 0.f, 0.f);
        if ((unsigned)gX <= 19u && (unsigned)gY <= 19u && (unsigned)gZ <= 19u)
            val = ((const float4*)Km)[((gX * NN + gY) * NN + gZ) * 16 + ch];
        const int b = row * 65 + ch * 4;
        u[b] = val.x; u[b + 1] = val.y; u[b + 2] = val.z; u[b + 3] = val.w;
    }
    __syncthreads();

    // geometry for p0 / p1c (digit-swap quirk)
    int e3 = p0 / 25, e4 = (p0 / 5) % 5, e5 = p0 % 5;
    const int row0 = 36 * (wx + e4) + 6 * (wy + e3) + (wz + e5);
    const bool mv0 = ((unsigned)(x + e3 - 3) <= 18u) &&
                     ((unsigned)(y + e4 - 3) <= 18u) &&
                     ((unsigned)(z + e5 - 3) <= 18u);
    e3 = p1c / 25; e4 = (p1c / 5) % 5; e5 = p1c % 5;
    const int row1 = 36 * (wx + e4) + 6 * (wy + e3) + (wz + e5);
    const bool mv1 = (p1 < NP) &&
                     ((unsigned)(x + e3 - 3) <= 18u) &&
                     ((unsigned)(y + e4 - 3) <= 18u) &&
                     ((unsigned)(z + e5 - 3) <= 18u);

    float a0 = rel0, a1 = rel1;
#pragma unroll
    for (int i = 0; i < 16; ++i) {
        const float qa = __shfl(q, 4 * i + 0);
        const float qb = __shfl(q, 4 * i + 1);
        const float qc = __shfl(q, 4 * i + 2);
        const float qd = __shfl(q, 4 * i + 3);
        const int b0 = row0 * 65 + 4 * i;
        const int b1 = row1 * 65 + 4 * i;
        a0 = fmaf(u[b0], qa, a0); a0 = fmaf(u[b0 + 1], qb, a0);
        a0 = fmaf(u[b0 + 2], qc, a0); a0 = fmaf(u[b0 + 3], qd, a0);
        a1 = fmaf(u[b1], qa, a1); a1 = fmaf(u[b1 + 1], qb, a1);
        a1 = fmaf(u[b1 + 2], qc, a1); a1 = fmaf(u[b1 + 3], qd, a1);
    }
    const float l0 = mv0 ? a0 : -1e9f;
    const float l1 = mv1 ? a1 : -1e9f;

    // ---- softmax over 125 ----
    float m = fmaxf(l0, l1);
#pragma unroll
    for (int d = 1; d < 64; d <<= 1) m = fmaxf(m, __shfl_xor(m, d));
    const float e0 = __expf(l0 - m);
    const float e1 = __expf(l1 - m);
    float ssum = e0 + e1;
#pragma unroll
    for (int d = 1; d < 64; d <<= 1) ssum += __shfl_xor(ssum, d);
    const float inv = 1.f / ssum;
    sc_s[w][p0] = e0 * inv;
    sc_s[w][p1] = e1 * inv;   // p1 up to 127; clamped lanes store exact 0
    __syncthreads();          // u(Km) reads + score writes done

    // ---- phase C: stage VW union ----
    for (int i = tid; i < 216 * 16; i += 512) {
        const int row = i >> 4, ch = i & 15;
        const int ux = row / 36, uy = (row / 6) % 6, uz = row % 6;
        const int gX = TX * 2 - 2 + ux;
        const int gY = TY * 2 - 2 + uy;
        const int gZ = TZ * 2 - 2 + uz;
        float4 val = make_float4(0.f, 0.f, 0.f, 0.f);
        if ((unsigned)gX <= 19u && (unsigned)gY <= 19u && (unsigned)gZ <= 19u)
            val = ((const float4*)VW)[((gX * NN + gY) * NN + gZ) * 16 + ch];
        const int b = row * 65 + ch * 4;
        u[b] = val.x; u[b + 1] = val.y; u[b + 2] = val.z; u[b + 3] = val.w;
    }
    __syncthreads();

    // ---- branch-free weighted sum: lane = channel ----
    // p = g*5 + j : e3 = g/5, e4 = g%5, e5 = j
    float A0 = 0.f, A1 = 0.f, A2 = 0.f, A3 = 0.f, A4 = 0.f;
#pragma unroll 5
    for (int g = 0; g < 25; ++g) {
        const int ge3 = g / 5, ge4 = g % 5;
        const int rb = 36 * (wx + ge4) + 6 * (wy + ge3) + wz;
        const int pb = g * 5;
        A0 = fmaf(sc_s[w][pb + 0], u[(rb + 0) * 65 + lane] + vrelW[(pb + 0) * 64 + lane], A0);
        A1 = fmaf(sc_s[w][pb + 1], u[(rb + 1) * 65 + lane] + vrelW[(pb + 1) * 64 + lane], A1);
        A2 = fmaf(sc_s[w][pb + 2], u[(rb + 2) * 65 + lane] + vrelW[(pb + 2) * 64 + lane], A2);
        A3 = fmaf(sc_s[w][pb + 3], u[(rb + 3) * 65 + lane] + vrelW[(pb + 3) * 64 + lane], A3);
        A4 = fmaf(sc_s[w][pb + 4], u[(rb + 4) * 65 + lane] + vrelW[(pb + 4) * 64 + lane], A4);
    }
    const float rw = ((A0 + A1) + (A2 + A3)) + A4;
    out[v * 64 + lane] = rw + bo[lane];
}

// ---------------------------------------------------------------------------
extern "C" void kernel_launch(void* const* d_in, const int* in_sizes, int n_in,
                              void* d_out, int out_size, void* d_ws, size_t ws_size,
                              hipStream_t stream) {
    const float* SE  = (const float*)d_in[0];
    const float* rpw = (const float*)d_in[1];
    const float* Wq  = (const float*)d_in[2];
    const float* bq  = (const float*)d_in[3];
    const float* Wk  = (const float*)d_in[4];
    const float* bk  = (const float*)d_in[5];
    const float* Wv  = (const float*)d_in[6];
    const float* bv  = (const float*)d_in[7];
    const float* Wo  = (const float*)d_in[8];
    const float* bo  = (const float*)d_in[9];
    float* out = (float*)d_out;

    float* ws    = (float*)d_ws;
    float* Q     = ws;                 // 8000*64
    float* Km    = ws + 512000;        // 8000*64
    float* VW    = ws + 1024000;       // 8000*64
    float* k_rel = ws + 1536000;       // 125*64
    float* vrelW = ws + 1544000;       // 125*64
    float* Wvo   = ws + 1552000;       // 64*64

    prep<<<NP + 64, 64, 0, stream>>>(rpw, Wk, bk, Wv, bv, Wo, k_rel, vrelW, Wvo);
    qkv2<<<NV / 32, 256, 0, stream>>>(SE, Wq, bq, Wk, Wvo, Q, Km, VW);
    attn3<<<1000, 512, 0, stream>>>(Q, Km, VW, k_rel, vrelW, bo, out);
}

// Round 6
// 134.876 us; speedup vs baseline: 1.7776x; 1.7776x over previous
//
#include <hip/hip_runtime.h>

#define NN 20
#define NP 125          // 5^3 window
#define NV (NN*NN*NN)   // 8000

// ---------------------------------------------------------------------------
// prep: blocks 0..124  -> k_rel[p][c]  = bk + relpos_flat[p] @ Wk[0:96]
//                         vrelW[p][c]  = (bv + relpos_flat[p] @ Wv[0:96]) @ Wo
//       blocks 125..188 -> Wvo[d][c]   = Wv[96+d][:] @ Wo     (64x64)
// ---------------------------------------------------------------------------
__global__ __launch_bounds__(64) void prep(
        const float* __restrict__ rpw,
        const float* __restrict__ Wk, const float* __restrict__ bk,
        const float* __restrict__ Wv, const float* __restrict__ bv,
        const float* __restrict__ Wo,
        float* __restrict__ k_rel, float* __restrict__ vrelW,
        float* __restrict__ Wvo) {
    const int c = threadIdx.x;
    if (blockIdx.x < NP) {
        const int p = blockIdx.x;
        const int d3 = p / 25, d4 = (p / 5) % 5, d5 = p % 5;
        __shared__ float vtmp[64];
        float ak = bk[c], av = bv[c];
#pragma unroll
        for (int t = 0; t < 96; ++t) {
            const int blk = t >> 5, off = t & 31;
            const int row = (blk == 0) ? d3 : (blk == 1) ? d4 : d5;
            const float r = rpw[row * 32 + off];
            ak = fmaf(r, Wk[t * 64 + c], ak);
            av = fmaf(r, Wv[t * 64 + c], av);
        }
        k_rel[p * 64 + c] = ak;
        vtmp[c] = av;
        __syncthreads();
        float o = 0.f;
#pragma unroll 8
        for (int e = 0; e < 64; ++e)
            o = fmaf(vtmp[e], Wo[e * 64 + c], o);
        vrelW[p * 64 + c] = o;
    } else {
        const int d = blockIdx.x - NP;
        float acc = 0.f;
#pragma unroll 8
        for (int e = 0; e < 64; ++e)
            acc = fmaf(Wv[(96 + d) * 64 + e], Wo[e * 64 + c], acc);
        Wvo[d * 64 + c] = acc;
    }
}

// ---------------------------------------------------------------------------
// qkv2: Q = SE@Wq + bq ; Km = SE@Wk[96:] ; VW = SE@Wvo
// 250 blocks x 256 threads, 32 voxels/block (8 per wave).
// ---------------------------------------------------------------------------
__global__ __launch_bounds__(256) void qkv2(
        const float* __restrict__ SE,
        const float* __restrict__ Wq, const float* __restrict__ bq,
        const float* __restrict__ Wk, const float* __restrict__ Wvo,
        float* __restrict__ Q, float* __restrict__ Km, float* __restrict__ VW) {
    __shared__ float se_s[32][65];
    const int t = threadIdx.x;
    const int vbase = blockIdx.x * 32;
    {   // stage 32x64 floats = 512 float4, 2 per thread
        const float4* __restrict__ src = (const float4*)(SE + vbase * 64);
        const float4 a = src[t];
        const float4 b = src[t + 256];
        const int r0 = t >> 4,        c0 = (t & 15) * 4;
        const int r1 = (t + 256) >> 4;
        se_s[r0][c0 + 0] = a.x; se_s[r0][c0 + 1] = a.y;
        se_s[r0][c0 + 2] = a.z; se_s[r0][c0 + 3] = a.w;
        se_s[r1][c0 + 0] = b.x; se_s[r1][c0 + 1] = b.y;
        se_s[r1][c0 + 2] = b.z; se_s[r1][c0 + 3] = b.w;
    }
    __syncthreads();
    const int lane = t & 63, w = t >> 6;
    float aq[8], ak[8], av[8];
#pragma unroll
    for (int j = 0; j < 8; ++j) { aq[j] = bq[lane]; ak[j] = 0.f; av[j] = 0.f; }
#pragma unroll 8
    for (int d = 0; d < 64; ++d) {
        const float wq = Wq[d * 64 + lane];
        const float wk = Wk[(96 + d) * 64 + lane];
        const float wv = Wvo[d * 64 + lane];
#pragma unroll
        for (int j = 0; j < 8; ++j) {
            const float s = se_s[w * 8 + j][d];   // uniform addr -> broadcast
            aq[j] = fmaf(s, wq, aq[j]);
            ak[j] = fmaf(s, wk, ak[j]);
            av[j] = fmaf(s, wv, av[j]);
        }
    }
#pragma unroll
    for (int j = 0; j < 8; ++j) {
        const int v = vbase + w * 8 + j;
        Q[v * 64 + lane]  = aq[j];
        Km[v * 64 + lane] = ak[j];
        VW[v * 64 + lane] = av[j];
    }
}

// ---------------------------------------------------------------------------
// attn4: block = 512 threads (8 waves) = 2x2x2 voxel tile; grid 1000.
// XCD-AWARE SWIZZLE: 10x10x10 tile grid = 2x2x2 arrangement of 5x5x5 chunks;
// hw round-robin puts bx%8 on XCD bx%8, so chunk (bx&7) = one XCD owning a
// cubic 10^3-voxel region (+halo = 14^3): Km/VW footprint ~1.4 MB -> L2-hot.
// LDS: one padded union buffer u[216][65] staged twice (Km then VW);
// stride 65 -> conflict-free compute reads. OOB rows zero-filled (reference
// zero padding). k_rel read directly from global (L1-hot, 2 rows/wave).
// REFERENCE QUIRKS: gather coord = (x+e4-2, y+e3-2, z+e5-2) [x/y digit swap];
// mask coord = (x+e3-2, y+e4-2, z+e5-2) in [1,19]^3; masked score exactly 0.
// ---------------------------------------------------------------------------
__global__ __launch_bounds__(512, 4) void attn4(
        const float* __restrict__ Q, const float* __restrict__ Km,
        const float* __restrict__ VW,
        const float* __restrict__ k_rel, const float* __restrict__ vrelW,
        const float* __restrict__ bo,
        float* __restrict__ out) {
    __shared__ float u[216 * 65];
    __shared__ float sc_s[8][128];

    const int tid  = threadIdx.x;
    const int lane = tid & 63;
    const int w    = tid >> 6;

    // ---- XCD-aware cubic chunking ----
    const int chunk = blockIdx.x & 7;          // hw XCD (round-robin)
    const int idx   = blockIdx.x >> 3;         // 0..124 within chunk
    const int cx = chunk >> 2, cy = (chunk >> 1) & 1, cz = chunk & 1;
    const int TX = cx * 5 + idx / 25;
    const int TY = cy * 5 + (idx / 5) % 5;
    const int TZ = cz * 5 + idx % 5;

    const int wx = w >> 2, wy = (w >> 1) & 1, wz = w & 1;
    const int x = TX * 2 + wx, y = TY * 2 + wy, z = TZ * 2 + wz;
    const int v = (x * NN + y) * NN + z;

    // ---- stage Km union (216 rows, zero-fill OOB) ----
    for (int i = tid; i < 216 * 16; i += 512) {
        const int row = i >> 4, ch = i & 15;
        const int ux = row / 36, uy = (row / 6) % 6, uz = row % 6;
        const int gX = TX * 2 - 2 + ux;
        const int gY = TY * 2 - 2 + uy;
        const int gZ = TZ * 2 - 2 + uz;
        float4 val = make_float4(0.f, 0.f, 0.f, 0.f);
        if ((unsigned)gX <= 19u && (unsigned)gY <= 19u && (unsigned)gZ <= 19u)
            val = ((const float4*)Km)[((gX * NN + gY) * NN + gZ) * 16 + ch];
        const int b = row * 65 + ch * 4;
        u[b] = val.x; u[b + 1] = val.y; u[b + 2] = val.z; u[b + 3] = val.w;
    }

    const float q = Q[v * 64 + lane];
    const int p0 = lane;
    const int p1 = lane + 64;
    const int p1c = (p1 < NP) ? p1 : (NP - 1);

    // geometry (digit-swap quirk)
    int e3 = p0 / 25, e4 = (p0 / 5) % 5, e5 = p0 % 5;
    const int row0 = 36 * (wx + e4) + 6 * (wy + e3) + (wz + e5);
    const bool mv0 = ((unsigned)(x + e3 - 3) <= 18u) &&
                     ((unsigned)(y + e4 - 3) <= 18u) &&
                     ((unsigned)(z + e5 - 3) <= 18u);
    e3 = p1c / 25; e4 = (p1c / 5) % 5; e5 = p1c % 5;
    const int row1 = 36 * (wx + e4) + 6 * (wy + e3) + (wz + e5);
    const bool mv1 = (p1 < NP) &&
                     ((unsigned)(x + e3 - 3) <= 18u) &&
                     ((unsigned)(y + e4 - 3) <= 18u) &&
                     ((unsigned)(z + e5 - 3) <= 18u);

    const float4* __restrict__ kr0 = (const float4*)(k_rel + p0 * 64);
    const float4* __restrict__ kr1 = (const float4*)(k_rel + p1c * 64);

    __syncthreads();   // Km union staged

    // ---- logits: Km from LDS + k_rel from global (L1-hot) ----
    float a0 = 0.f, a1 = 0.f;
#pragma unroll
    for (int i = 0; i < 16; ++i) {
        const float qa = __shfl(q, 4 * i + 0);
        const float qb = __shfl(q, 4 * i + 1);
        const float qc = __shfl(q, 4 * i + 2);
        const float qd = __shfl(q, 4 * i + 3);
        const float4 r0 = kr0[i], r1 = kr1[i];
        const int b0 = row0 * 65 + 4 * i;
        const int b1 = row1 * 65 + 4 * i;
        a0 = fmaf(u[b0] + r0.x, qa, a0);
        a0 = fmaf(u[b0 + 1] + r0.y, qb, a0);
        a0 = fmaf(u[b0 + 2] + r0.z, qc, a0);
        a0 = fmaf(u[b0 + 3] + r0.w, qd, a0);
        a1 = fmaf(u[b1] + r1.x, qa, a1);
        a1 = fmaf(u[b1 + 1] + r1.y, qb, a1);
        a1 = fmaf(u[b1 + 2] + r1.z, qc, a1);
        a1 = fmaf(u[b1 + 3] + r1.w, qd, a1);
    }
    const float l0 = mv0 ? a0 : -1e9f;
    const float l1 = mv1 ? a1 : -1e9f;

    // ---- softmax over 125 ----
    float m = fmaxf(l0, l1);
#pragma unroll
    for (int d = 1; d < 64; d <<= 1) m = fmaxf(m, __shfl_xor(m, d));
    const float e0 = __expf(l0 - m);
    const float e1 = __expf(l1 - m);
    float ssum = e0 + e1;
#pragma unroll
    for (int d = 1; d < 64; d <<= 1) ssum += __shfl_xor(ssum, d);
    const float inv = 1.f / ssum;
    sc_s[w][p0] = e0 * inv;
    sc_s[w][p1] = e1 * inv;   // p1 up to 127; clamped lanes store exact 0
    __syncthreads();          // all u(Km) reads done + scores visible

    // ---- stage VW union ----
    for (int i = tid; i < 216 * 16; i += 512) {
        const int row = i >> 4, ch = i & 15;
        const int ux = row / 36, uy = (row / 6) % 6, uz = row % 6;
        const int gX = TX * 2 - 2 + ux;
        const int gY = TY * 2 - 2 + uy;
        const int gZ = TZ * 2 - 2 + uz;
        float4 val = make_float4(0.f, 0.f, 0.f, 0.f);
        if ((unsigned)gX <= 19u && (unsigned)gY <= 19u && (unsigned)gZ <= 19u)
            val = ((const float4*)VW)[((gX * NN + gY) * NN + gZ) * 16 + ch];
        const int b = row * 65 + ch * 4;
        u[b] = val.x; u[b + 1] = val.y; u[b + 2] = val.z; u[b + 3] = val.w;
    }
    __syncthreads();

    // ---- branch-free weighted sum: lane = channel ----
    // p = g*5 + j : e3 = g/5, e4 = g%5, e5 = j
    float A0 = 0.f, A1 = 0.f, A2 = 0.f, A3 = 0.f, A4 = 0.f;
    const float* __restrict__ vr = vrelW + lane;
#pragma unroll 5
    for (int g = 0; g < 25; ++g) {
        const int ge3 = g / 5, ge4 = g % 5;
        const int rb = 36 * (wx + ge4) + 6 * (wy + ge3) + wz;
        const int pb = g * 5;
        A0 = fmaf(sc_s[w][pb + 0], u[(rb + 0) * 65 + lane] + vr[(pb + 0) * 64], A0);
        A1 = fmaf(sc_s[w][pb + 1], u[(rb + 1) * 65 + lane] + vr[(pb + 1) * 64], A1);
        A2 = fmaf(sc_s[w][pb + 2], u[(rb + 2) * 65 + lane] + vr[(pb + 2) * 64], A2);
        A3 = fmaf(sc_s[w][pb + 3], u[(rb + 3) * 65 + lane] + vr[(pb + 3) * 64], A3);
        A4 = fmaf(sc_s[w][pb + 4], u[(rb + 4) * 65 + lane] + vr[(pb + 4) * 64], A4);
    }
    const float rw = ((A0 + A1) + (A2 + A3)) + A4;
    out[v * 64 + lane] = rw + bo[lane];
}

// ---------------------------------------------------------------------------
extern "C" void kernel_launch(void* const* d_in, const int* in_sizes, int n_in,
                              void* d_out, int out_size, void* d_ws, size_t ws_size,
                              hipStream_t stream) {
    const float* SE  = (const float*)d_in[0];
    const float* rpw = (const float*)d_in[1];
    const float* Wq  = (const float*)d_in[2];
    const float* bq  = (const float*)d_in[3];
    const float* Wk  = (const float*)d_in[4];
    const float* bk  = (const float*)d_in[5];
    const float* Wv  = (const float*)d_in[6];
    const float* bv  = (const float*)d_in[7];
    const float* Wo  = (const float*)d_in[8];
    const float* bo  = (const float*)d_in[9];
    float* out = (float*)d_out;

    float* ws    = (float*)d_ws;
    float* Q     = ws;                 // 8000*64
    float* Km    = ws + 512000;        // 8000*64
    float* VW    = ws + 1024000;       // 8000*64
    float* k_rel = ws + 1536000;       // 125*64
    float* vrelW = ws + 1544000;       // 125*64
    float* Wvo   = ws + 1552000;       // 64*64

    prep<<<NP + 64, 64, 0, stream>>>(rpw, Wk, bk, Wv, bv, Wo, k_rel, vrelW, Wvo);
    qkv2<<<NV / 32, 256, 0, stream>>>(SE, Wq, bq, Wk, Wvo, Q, Km, VW);
    attn4<<<1000, 512, 0, stream>>>(Q, Km, VW, k_rel, vrelW, bo, out);
}